// Round 20
// baseline (104.583 us; speedup 1.0000x reference)
//
#include <hip/hip_runtime.h>
#include <hip/hip_bf16.h>
#include <math.h>

// Problem constants
#define LSEQ 2048
#define DMODEL 768
#define NHEAD 12
#define DHEAD 64
#define D3 2304
#define EPSLN 1e-5f
#define NSEG 2
#define SEGTILES 16      // 32 KV tiles / NSEG
#define LOG2E 1.44269504088896f

typedef __attribute__((ext_vector_type(8))) short short8;
typedef __attribute__((ext_vector_type(4))) short s16x4;
typedef __attribute__((ext_vector_type(4))) float f32x4;
typedef __attribute__((ext_vector_type(4))) unsigned short u16x4;

static __device__ __forceinline__ unsigned short f2bf(float x) {
    __hip_bfloat16 b = __float2bfloat16(x);
    return *reinterpret_cast<unsigned short*>(&b);
}
static __device__ __forceinline__ float bf2f(unsigned short u) {
    __hip_bfloat16 b = *reinterpret_cast<__hip_bfloat16*>(&u);
    return __bfloat162float(b);
}

// ---------------------------------------------------------------------------
// Kernel 1 (merged): bx < LSEQ -> LayerNorm row (bf16 hi only); else weight
// transpose + Dekker split tile (w_qkv then w_out).
// ---------------------------------------------------------------------------
__global__ __launch_bounds__(256) void prep1_kernel(const float* __restrict__ x,
                                                    const float* __restrict__ lw,
                                                    const float* __restrict__ lb,
                                                    unsigned short* __restrict__ hhi,
                                                    const float* __restrict__ Wq,
                                                    unsigned short* __restrict__ Tqh,
                                                    unsigned short* __restrict__ Tql,
                                                    const float* __restrict__ Wo,
                                                    unsigned short* __restrict__ Toh,
                                                    unsigned short* __restrict__ Tol) {
    __shared__ float smem[64 * 65];
    int bx = blockIdx.x;
    int tid = threadIdx.x;

    if (bx < LSEQ) {
        int row = bx;
        const float* xr = x + (size_t)row * DMODEL;
        float s = 0.f, s2 = 0.f;
        for (int i = tid; i < DMODEL; i += 256) {
            float v = xr[i];
            s += v; s2 += v * v;
        }
        for (int o = 32; o > 0; o >>= 1) { s += __shfl_down(s, o); s2 += __shfl_down(s2, o); }
        int wid = tid >> 6, lane = tid & 63;
        if (lane == 0) { smem[wid] = s; smem[4 + wid] = s2; }
        __syncthreads();
        s = smem[0] + smem[1] + smem[2] + smem[3];
        s2 = smem[4] + smem[5] + smem[6] + smem[7];
        float mean = s * (1.0f / DMODEL);
        float var = s2 * (1.0f / DMODEL) - mean * mean;
        float r = rsqrtf(var + EPSLN);
        for (int i = tid; i < DMODEL; i += 256) {
            float y = (xr[i] - mean) * r * lw[i] + lb[i];
            hhi[(size_t)row * DMODEL + i] = f2bf(y);
        }
    } else {
        int tb = bx - LSEQ;
        int nt = tb % (D3 / 64 + DMODEL / 64);
        int kt = tb / (D3 / 64 + DMODEL / 64);
        const float* W;
        unsigned short *Thi, *Tlo;
        int N, n0;
        if (nt < D3 / 64) { W = Wq; Thi = Tqh; Tlo = Tql; N = D3; n0 = nt * 64; }
        else              { W = Wo; Thi = Toh; Tlo = Tol; N = DMODEL; n0 = (nt - D3 / 64) * 64; }
        const int K = DMODEL;
        int k0 = kt * 64;
        float (*tile)[65] = (float(*)[65])smem;
        for (int e = tid; e < 4096; e += 256) {
            int r = e >> 6, c = e & 63;
            tile[r][c] = W[(size_t)(k0 + r) * N + n0 + c];
        }
        __syncthreads();
        for (int e = tid; e < 4096; e += 256) {
            int r = e >> 6, c = e & 63;
            float v = tile[c][r];
            unsigned short hi = f2bf(v);
            size_t idx = (size_t)(n0 + r) * K + k0 + c;
            Thi[idx] = hi;
            Tlo[idx] = f2bf(v - bf2f(hi));
        }
    }
}

// ---------------------------------------------------------------------------
// Kernel 2a: GEMM with A bf16-only, B split: C = A @ (Bh+Bl)^T (qkv proj).
// ---------------------------------------------------------------------------
__global__ __launch_bounds__(256) void gemm_bA(const unsigned short* __restrict__ Ahi,
                                               const unsigned short* __restrict__ Bhi,
                                               const unsigned short* __restrict__ Blo,
                                               float* __restrict__ C,
                                               int M, int N, int K) {
    __shared__ __align__(16) unsigned short Ah[64 * 64];
    __shared__ __align__(16) unsigned short Bh[64 * 64];
    __shared__ __align__(16) unsigned short Bl[64 * 64];

    int bx = blockIdx.x, by = blockIdx.y;
    int tid = threadIdx.x;
    int w = tid >> 6, lane = tid & 63;
    int g = lane >> 4, l16 = lane & 15;
    int wm = w >> 1, wn = w & 1;

    f32x4 acc[2][2] = {};

    for (int k0 = 0; k0 < K; k0 += 64) {
        __syncthreads();
#pragma unroll
        for (int c = 0; c < 2; ++c) {
            int slotb = c * 256 + w * 64;
            int slot = slotb + lane;
            int row = slot >> 3;
            int ss = (slot & 7) ^ (row & 7);
            size_t offA = (size_t)(by * 64 + row) * K + k0 + ss * 8;
            size_t offB = (size_t)(bx * 64 + row) * K + k0 + ss * 8;
            __builtin_amdgcn_global_load_lds(
                (const __attribute__((address_space(1))) unsigned int*)(Ahi + offA),
                (__attribute__((address_space(3))) unsigned int*)&Ah[(size_t)slotb * 8], 16, 0, 0);
            __builtin_amdgcn_global_load_lds(
                (const __attribute__((address_space(1))) unsigned int*)(Bhi + offB),
                (__attribute__((address_space(3))) unsigned int*)&Bh[(size_t)slotb * 8], 16, 0, 0);
            __builtin_amdgcn_global_load_lds(
                (const __attribute__((address_space(1))) unsigned int*)(Blo + offB),
                (__attribute__((address_space(3))) unsigned int*)&Bl[(size_t)slotb * 8], 16, 0, 0);
        }
        __syncthreads();

#pragma unroll
        for (int kk = 0; kk < 2; ++kk) {
            short8 a_h[2], b_h[2], b_l[2];
#pragma unroll
            for (int i = 0; i < 2; ++i) {
                int row = wm * 32 + i * 16 + l16;
                int s = (kk * 4 + g) ^ (row & 7);
                a_h[i] = *(const short8*)&Ah[row * 64 + s * 8];
            }
#pragma unroll
            for (int j = 0; j < 2; ++j) {
                int row = wn * 32 + j * 16 + l16;
                int s = (kk * 4 + g) ^ (row & 7);
                b_h[j] = *(const short8*)&Bh[row * 64 + s * 8];
                b_l[j] = *(const short8*)&Bl[row * 64 + s * 8];
            }
#pragma unroll
            for (int i = 0; i < 2; ++i)
#pragma unroll
                for (int j = 0; j < 2; ++j) {
                    acc[i][j] = __builtin_amdgcn_mfma_f32_16x16x32_bf16(a_h[i], b_h[j], acc[i][j], 0, 0, 0);
                    acc[i][j] = __builtin_amdgcn_mfma_f32_16x16x32_bf16(a_h[i], b_l[j], acc[i][j], 0, 0, 0);
                }
        }
    }

#pragma unroll
    for (int i = 0; i < 2; ++i)
#pragma unroll
        for (int j = 0; j < 2; ++j)
#pragma unroll
            for (int r = 0; r < 4; ++r) {
                int m = by * 64 + wm * 32 + i * 16 + g * 4 + r;
                int n = bx * 64 + wn * 32 + j * 16 + l16;
                C[(size_t)m * N + n] = acc[i][j][r];
            }
}

// ---------------------------------------------------------------------------
// Kernel 2b: full split-bf16 GEMM (A and B hi/lo), 3 MFMAs/pair (fallback).
// ---------------------------------------------------------------------------
__global__ __launch_bounds__(256) void gemm_split(const unsigned short* __restrict__ Ahi,
                                                  const unsigned short* __restrict__ Alo,
                                                  const unsigned short* __restrict__ Bhi,
                                                  const unsigned short* __restrict__ Blo,
                                                  float* __restrict__ C,
                                                  int M, int N, int K) {
    __shared__ __align__(16) unsigned short Ah[64 * 64];
    __shared__ __align__(16) unsigned short Al[64 * 64];
    __shared__ __align__(16) unsigned short Bh[64 * 64];
    __shared__ __align__(16) unsigned short Bl[64 * 64];

    int bx = blockIdx.x, by = blockIdx.y;
    int tid = threadIdx.x;
    int w = tid >> 6, lane = tid & 63;
    int g = lane >> 4, l16 = lane & 15;
    int wm = w >> 1, wn = w & 1;

    f32x4 acc[2][2] = {};

    for (int k0 = 0; k0 < K; k0 += 64) {
        __syncthreads();
#pragma unroll
        for (int c = 0; c < 2; ++c) {
            int slotb = c * 256 + w * 64;
            int slot = slotb + lane;
            int row = slot >> 3;
            int ss = (slot & 7) ^ (row & 7);
            size_t offA = (size_t)(by * 64 + row) * K + k0 + ss * 8;
            size_t offB = (size_t)(bx * 64 + row) * K + k0 + ss * 8;
            __builtin_amdgcn_global_load_lds(
                (const __attribute__((address_space(1))) unsigned int*)(Ahi + offA),
                (__attribute__((address_space(3))) unsigned int*)&Ah[(size_t)slotb * 8], 16, 0, 0);
            __builtin_amdgcn_global_load_lds(
                (const __attribute__((address_space(1))) unsigned int*)(Alo + offA),
                (__attribute__((address_space(3))) unsigned int*)&Al[(size_t)slotb * 8], 16, 0, 0);
            __builtin_amdgcn_global_load_lds(
                (const __attribute__((address_space(1))) unsigned int*)(Bhi + offB),
                (__attribute__((address_space(3))) unsigned int*)&Bh[(size_t)slotb * 8], 16, 0, 0);
            __builtin_amdgcn_global_load_lds(
                (const __attribute__((address_space(1))) unsigned int*)(Blo + offB),
                (__attribute__((address_space(3))) unsigned int*)&Bl[(size_t)slotb * 8], 16, 0, 0);
        }
        __syncthreads();

#pragma unroll
        for (int kk = 0; kk < 2; ++kk) {
            short8 a_h[2], a_l[2], b_h[2], b_l[2];
#pragma unroll
            for (int i = 0; i < 2; ++i) {
                int row = wm * 32 + i * 16 + l16;
                int s = (kk * 4 + g) ^ (row & 7);
                a_h[i] = *(const short8*)&Ah[row * 64 + s * 8];
                a_l[i] = *(const short8*)&Al[row * 64 + s * 8];
            }
#pragma unroll
            for (int j = 0; j < 2; ++j) {
                int row = wn * 32 + j * 16 + l16;
                int s = (kk * 4 + g) ^ (row & 7);
                b_h[j] = *(const short8*)&Bh[row * 64 + s * 8];
                b_l[j] = *(const short8*)&Bl[row * 64 + s * 8];
            }
#pragma unroll
            for (int i = 0; i < 2; ++i)
#pragma unroll
                for (int j = 0; j < 2; ++j) {
                    acc[i][j] = __builtin_amdgcn_mfma_f32_16x16x32_bf16(a_h[i], b_h[j], acc[i][j], 0, 0, 0);
                    acc[i][j] = __builtin_amdgcn_mfma_f32_16x16x32_bf16(a_h[i], b_l[j], acc[i][j], 0, 0, 0);
                    acc[i][j] = __builtin_amdgcn_mfma_f32_16x16x32_bf16(a_l[i], b_h[j], acc[i][j], 0, 0, 0);
                }
        }
    }

#pragma unroll
    for (int i = 0; i < 2; ++i)
#pragma unroll
        for (int j = 0; j < 2; ++j)
#pragma unroll
            for (int r = 0; r < 4; ++r) {
                int m = by * 64 + wm * 32 + i * 16 + g * 4 + r;
                int n = bx * 64 + wn * 32 + j * 16 + l16;
                C[(size_t)m * N + n] = acc[i][j][r];
            }
}

// ---------------------------------------------------------------------------
// Kernel 2c: out-proj GEMM with FUSED combine. A = (Opart0+Opart1)*rinv,
// Dekker-split in registers, ds_write into the same swizzled layout
// (granule p of row holds source granule p^(row&7)). BK=64=DHEAD, so each
// k-iter maps to one head h=k0/64 and rinv is per-(row,h).
// ---------------------------------------------------------------------------
__global__ __launch_bounds__(256) void gemm_out_fused(const float* __restrict__ Opart,
                                                      const float* __restrict__ Lpart,
                                                      const unsigned short* __restrict__ Bhi,
                                                      const unsigned short* __restrict__ Blo,
                                                      float* __restrict__ C) {
    const int M = LSEQ, N = DMODEL, K = DMODEL;
    __shared__ __align__(16) unsigned short Ah[64 * 64];
    __shared__ __align__(16) unsigned short Al[64 * 64];
    __shared__ __align__(16) unsigned short Bh[64 * 64];
    __shared__ __align__(16) unsigned short Bl[64 * 64];

    int bx = blockIdx.x, by = blockIdx.y;
    int tid = threadIdx.x;
    int w = tid >> 6, lane = tid & 63;
    int g = lane >> 4, l16 = lane & 15;
    int wm = w >> 1, wn = w & 1;

    f32x4 acc[2][2] = {};

    for (int k0 = 0; k0 < K; k0 += 64) {
        int h = k0 >> 6;
        __syncthreads();
        // ---- B: async global_load_lds staging (unchanged) ----
#pragma unroll
        for (int c = 0; c < 2; ++c) {
            int slotb = c * 256 + w * 64;
            int slot = slotb + lane;
            int row = slot >> 3;
            int ss = (slot & 7) ^ (row & 7);
            size_t offB = (size_t)(bx * 64 + row) * K + k0 + ss * 8;
            __builtin_amdgcn_global_load_lds(
                (const __attribute__((address_space(1))) unsigned int*)(Bhi + offB),
                (__attribute__((address_space(3))) unsigned int*)&Bh[(size_t)slotb * 8], 16, 0, 0);
            __builtin_amdgcn_global_load_lds(
                (const __attribute__((address_space(1))) unsigned int*)(Blo + offB),
                (__attribute__((address_space(3))) unsigned int*)&Bl[(size_t)slotb * 8], 16, 0, 0);
        }
        // ---- A: reg-staged combine + split -> swizzled ds_write ----
#pragma unroll
        for (int c = 0; c < 2; ++c) {
            int slot = c * 256 + tid;
            int row = slot >> 3;      // row within tile
            int p = slot & 7;         // dest granule
            int cg = p ^ (row & 7);   // source granule
            int q = by * 64 + row;
            const float* o0 = &Opart[((size_t)0 * LSEQ + q) * DMODEL + k0 + cg * 8];
            const float* o1 = &Opart[((size_t)1 * LSEQ + q) * DMODEL + k0 + cg * 8];
            float denom = Lpart[((size_t)0 * NHEAD + h) * LSEQ + q] +
                          Lpart[((size_t)1 * NHEAD + h) * LSEQ + q];
            float rinv = 1.0f / denom;
            float4 s00 = *(const float4*)o0;
            float4 s01 = *(const float4*)(o0 + 4);
            float4 s10 = *(const float4*)o1;
            float4 s11 = *(const float4*)(o1 + 4);
            float v0 = (s00.x + s10.x) * rinv, v1 = (s00.y + s10.y) * rinv;
            float v2 = (s00.z + s10.z) * rinv, v3 = (s00.w + s10.w) * rinv;
            float v4 = (s01.x + s11.x) * rinv, v5 = (s01.y + s11.y) * rinv;
            float v6 = (s01.z + s11.z) * rinv, v7 = (s01.w + s11.w) * rinv;
            short8 hi8, lo8;
            hi8[0] = (short)f2bf(v0); lo8[0] = (short)f2bf(v0 - bf2f((unsigned short)hi8[0]));
            hi8[1] = (short)f2bf(v1); lo8[1] = (short)f2bf(v1 - bf2f((unsigned short)hi8[1]));
            hi8[2] = (short)f2bf(v2); lo8[2] = (short)f2bf(v2 - bf2f((unsigned short)hi8[2]));
            hi8[3] = (short)f2bf(v3); lo8[3] = (short)f2bf(v3 - bf2f((unsigned short)hi8[3]));
            hi8[4] = (short)f2bf(v4); lo8[4] = (short)f2bf(v4 - bf2f((unsigned short)hi8[4]));
            hi8[5] = (short)f2bf(v5); lo8[5] = (short)f2bf(v5 - bf2f((unsigned short)hi8[5]));
            hi8[6] = (short)f2bf(v6); lo8[6] = (short)f2bf(v6 - bf2f((unsigned short)hi8[6]));
            hi8[7] = (short)f2bf(v7); lo8[7] = (short)f2bf(v7 - bf2f((unsigned short)hi8[7]));
            *(short8*)&Ah[row * 64 + p * 8] = hi8;
            *(short8*)&Al[row * 64 + p * 8] = lo8;
        }
        __syncthreads();

#pragma unroll
        for (int kk = 0; kk < 2; ++kk) {
            short8 a_h[2], a_l[2], b_h[2], b_l[2];
#pragma unroll
            for (int i = 0; i < 2; ++i) {
                int row = wm * 32 + i * 16 + l16;
                int s = (kk * 4 + g) ^ (row & 7);
                a_h[i] = *(const short8*)&Ah[row * 64 + s * 8];
                a_l[i] = *(const short8*)&Al[row * 64 + s * 8];
            }
#pragma unroll
            for (int j = 0; j < 2; ++j) {
                int row = wn * 32 + j * 16 + l16;
                int s = (kk * 4 + g) ^ (row & 7);
                b_h[j] = *(const short8*)&Bh[row * 64 + s * 8];
                b_l[j] = *(const short8*)&Bl[row * 64 + s * 8];
            }
#pragma unroll
            for (int i = 0; i < 2; ++i)
#pragma unroll
                for (int j = 0; j < 2; ++j) {
                    acc[i][j] = __builtin_amdgcn_mfma_f32_16x16x32_bf16(a_h[i], b_h[j], acc[i][j], 0, 0, 0);
                    acc[i][j] = __builtin_amdgcn_mfma_f32_16x16x32_bf16(a_h[i], b_l[j], acc[i][j], 0, 0, 0);
                    acc[i][j] = __builtin_amdgcn_mfma_f32_16x16x32_bf16(a_l[i], b_h[j], acc[i][j], 0, 0, 0);
                }
        }
    }

#pragma unroll
    for (int i = 0; i < 2; ++i)
#pragma unroll
        for (int j = 0; j < 2; ++j)
#pragma unroll
            for (int r = 0; r < 4; ++r) {
                int m = by * 64 + wm * 32 + i * 16 + g * 4 + r;
                int n = bx * 64 + wn * 32 + j * 16 + l16;
                C[(size_t)m * N + n] = acc[i][j][r];
            }
}

// ---------------------------------------------------------------------------
// Kernel 3 (merged): bx < LSEQ -> qk-LN+RoPE token; else V-transpose tile.
// ---------------------------------------------------------------------------
__global__ __launch_bounds__(256) void prep2_kernel(const float* __restrict__ qkv,
                                                    const float* __restrict__ qw,
                                                    const float* __restrict__ kw,
                                                    __hip_bfloat16* __restrict__ qh,
                                                    __hip_bfloat16* __restrict__ kh,
                                                    __hip_bfloat16* __restrict__ vt) {
    __shared__ float smem[64 * 65];
    int bx = blockIdx.x;
    int tid = threadIdx.x;

    if (bx < LSEQ) {
        int l = bx;
        const float* qr = qkv + (size_t)l * D3;
        const float* kr = qr + DMODEL;

        float sq = 0.f, sq2 = 0.f, sk = 0.f, sk2 = 0.f;
        for (int i = tid; i < DMODEL; i += 256) {
            float a = qr[i]; sq += a; sq2 += a * a;
            float b = kr[i]; sk += b; sk2 += b * b;
        }
        for (int o = 32; o > 0; o >>= 1) {
            sq += __shfl_down(sq, o); sq2 += __shfl_down(sq2, o);
            sk += __shfl_down(sk, o); sk2 += __shfl_down(sk2, o);
        }
        int wid = tid >> 6, lane = tid & 63;
        if (lane == 0) { smem[wid] = sq; smem[4 + wid] = sq2; smem[8 + wid] = sk; smem[12 + wid] = sk2; }
        __syncthreads();
        sq = smem[0] + smem[1] + smem[2] + smem[3];
        sq2 = smem[4] + smem[5] + smem[6] + smem[7];
        sk = smem[8] + smem[9] + smem[10] + smem[11];
        sk2 = smem[12] + smem[13] + smem[14] + smem[15];
        float mq = sq * (1.0f / DMODEL);
        float vq = sq2 * (1.0f / DMODEL) - mq * mq;
        float rq = rsqrtf(vq + EPSLN);
        float mk = sk * (1.0f / DMODEL);
        float vk = sk2 * (1.0f / DMODEL) - mk * mk;
        float rk = rsqrtf(vk + EPSLN);

        const float LN10000 = 9.210340371976184f;
        const float QSCL = 0.125f * LOG2E;
        for (int p = tid; p < NHEAD * 32; p += 256) {
            int h = p >> 5, j = p & 31;
            int i1 = h * DHEAD + j;
            int i2 = i1 + 32;
            float q1 = (qr[i1] - mq) * rq * qw[i1];
            float q2 = (qr[i2] - mq) * rq * qw[i2];
            float k1 = (kr[i1] - mk) * rk * kw[i1];
            float k2 = (kr[i2] - mk) * rk * kw[i2];
            float inv = __expf(-LN10000 * (float)(2 * j) * (1.0f / DHEAD));
            float ang = (float)l * inv;
            float c, s;
            __sincosf(ang, &s, &c);
            size_t base = ((size_t)h * LSEQ + l) * DHEAD;
            qh[base + j]      = __float2bfloat16((q1 * c - q2 * s) * QSCL);
            qh[base + 32 + j] = __float2bfloat16((q2 * c + q1 * s) * QSCL);
            kh[base + j]      = __float2bfloat16(k1 * c - k2 * s);
            kh[base + 32 + j] = __float2bfloat16(k2 * c + k1 * s);
        }
    } else {
        int tb = bx - LSEQ;        // 0 .. 32*12-1
        int t = tb & 31, h = tb >> 5;
        float (*tile)[65] = (float(*)[65])smem;
        for (int e = tid; e < 4096; e += 256) {
            int tok = e >> 6, d = e & 63;
            tile[tok][d] = qkv[(size_t)(t * 64 + tok) * D3 + 2 * DMODEL + h * DHEAD + d];
        }
        __syncthreads();
        for (int e = tid; e < 4096; e += 256) {
            int d = e >> 6, tok = e & 63;
            vt[((size_t)h * DHEAD + d) * LSEQ + t * 64 + tok] = __float2bfloat16(tile[tok][d]);
        }
    }
}

// ---------------------------------------------------------------------------
// Kernel 4: MFMA flash attention, swapped QK^T, fixed-max exp2 softmax,
// in-register P, 2-phase pipelined staging, fused QK->exp2->pack.
// NSEG=2: grid 32x12x2 = 768 blocks = exactly 3/CU.
// ---------------------------------------------------------------------------
template <bool PARTIAL>
__global__ __launch_bounds__(256, 4) void attn_mfma(const __hip_bfloat16* __restrict__ qh,
                                                    const __hip_bfloat16* __restrict__ kh,
                                                    const __hip_bfloat16* __restrict__ vt,
                                                    const int* __restrict__ seq,
                                                    unsigned short* __restrict__ ctx_hi,
                                                    unsigned short* __restrict__ ctx_lo,
                                                    float* __restrict__ Opart,
                                                    float* __restrict__ Lpart) {
    int h = blockIdx.y;
    int q0 = blockIdx.x * 64;
    int sg = PARTIAL ? blockIdx.z : 0;
    int tid = threadIdx.x;
    int w = tid >> 6, lane = tid & 63;
    int g = lane >> 4, l16 = lane & 15;

    __shared__ __align__(16) unsigned short Klds[2][64 * 64];
    __shared__ __align__(16) unsigned short Vlds[2][64 * 64];
    __shared__ __align__(16) int seq_lds[2][64];

    int qrow = q0 + w * 16 + l16;
    short8 qfrag[2];
    {
        const short8* qp = (const short8*)(qh + ((size_t)h * LSEQ + qrow) * DHEAD);
        qfrag[0] = qp[g];
        qfrag[1] = qp[4 + g];
    }
    int seq_q = seq[qrow];

    f32x4 O[4] = {};
    float lrow = 0.f;

    int t0 = PARTIAL ? sg * SEGTILES : 0;
    int t1 = PARTIAL ? t0 + SEGTILES : LSEQ / 64;

    auto STAGE = [&](int buf, int t) {
#pragma unroll
        for (int i = 0; i < 2; ++i) {
            int c = 2 * w + i;
            int s = c * 64 + lane;
            int tok = s >> 3, d0 = (s & 7) * 8;
            const __hip_bfloat16* ksrc =
                kh + ((size_t)h * LSEQ + t * 64 + tok) * DHEAD + (d0 ^ ((tok & 7) << 3));
            __builtin_amdgcn_global_load_lds(
                (const __attribute__((address_space(1))) unsigned int*)ksrc,
                (__attribute__((address_space(3))) unsigned int*)&Klds[buf][c * 512],
                16, 0, 0);
            int d = s >> 3, u0 = (s & 7) * 8;
            const __hip_bfloat16* vsrc =
                vt + ((size_t)h * DHEAD + d) * LSEQ + t * 64 + (u0 ^ ((d & 7) << 3));
            __builtin_amdgcn_global_load_lds(
                (const __attribute__((address_space(1))) unsigned int*)vsrc,
                (__attribute__((address_space(3))) unsigned int*)&Vlds[buf][c * 512],
                16, 0, 0);
        }
        if (tid < 64) seq_lds[buf][tid] = seq[t * 64 + tid];
    };

    STAGE(0, t0);
    __syncthreads();

    for (int t = t0; t < t1; ++t) {
        int cur = (t - t0) & 1;
        if (t + 1 < t1) STAGE(cur ^ 1, t + 1);

        const unsigned short* Kb = Klds[cur];
        const unsigned short* Vb = Vlds[cur];

        short8 pa0, pa1;
#pragma unroll
        for (int nt = 0; nt < 4; ++nt) {
            int tok = nt * 16 + l16;
            short8 a0 = *(const short8*)&Kb[tok * 64 + ((g * 8) ^ ((tok & 7) << 3))];
            short8 a1 = *(const short8*)&Kb[tok * 64 + ((32 + g * 8) ^ ((tok & 7) << 3))];
            f32x4 acc = {0.f, 0.f, 0.f, 0.f};
            acc = __builtin_amdgcn_mfma_f32_16x16x32_bf16(a0, qfrag[0], acc, 0, 0, 0);
            acc = __builtin_amdgcn_mfma_f32_16x16x32_bf16(a1, qfrag[1], acc, 0, 0, 0);
            int4 sk4 = *(const int4*)&seq_lds[cur][nt * 16 + g * 4];
            float pv0 = exp2f(acc[0] + ((sk4.x == seq_q) ? LOG2E : 0.0f));
            float pv1 = exp2f(acc[1] + ((sk4.y == seq_q) ? LOG2E : 0.0f));
            float pv2 = exp2f(acc[2] + ((sk4.z == seq_q) ? LOG2E : 0.0f));
            float pv3 = exp2f(acc[3] + ((sk4.w == seq_q) ? LOG2E : 0.0f));
            lrow += pv0 + pv1 + pv2 + pv3;
            int hh = (nt & 1) * 4;
            if (nt < 2) {
                pa0[hh + 0] = (short)f2bf(pv0); pa0[hh + 1] = (short)f2bf(pv1);
                pa0[hh + 2] = (short)f2bf(pv2); pa0[hh + 3] = (short)f2bf(pv3);
            } else {
                pa1[hh + 0] = (short)f2bf(pv0); pa1[hh + 1] = (short)f2bf(pv1);
                pa1[hh + 2] = (short)f2bf(pv2); pa1[hh + 3] = (short)f2bf(pv3);
            }
        }

#pragma unroll
        for (int ntd = 0; ntd < 4; ++ntd) {
            int d = ntd * 16 + l16;
            int e = (d & 7) << 1;
            const unsigned short* Vr = &Vb[d * 64];
            s16x4 x0 = *(const s16x4*)&Vr[((g ^ e)) << 2];
            s16x4 x1 = *(const s16x4*)&Vr[(((4 + g) ^ e)) << 2];
            s16x4 x2 = *(const s16x4*)&Vr[(((8 + g) ^ e)) << 2];
            s16x4 x3 = *(const s16x4*)&Vr[(((12 + g) ^ e)) << 2];
            short8 vb0 = __builtin_shufflevector(x0, x1, 0, 1, 2, 3, 4, 5, 6, 7);
            short8 vb1 = __builtin_shufflevector(x2, x3, 0, 1, 2, 3, 4, 5, 6, 7);
            O[ntd] = __builtin_amdgcn_mfma_f32_16x16x32_bf16(pa0, vb0, O[ntd], 0, 0, 0);
            O[ntd] = __builtin_amdgcn_mfma_f32_16x16x32_bf16(pa1, vb1, O[ntd], 0, 0, 0);
        }

        __syncthreads();
    }

    lrow += __shfl_xor(lrow, 16, 64);
    lrow += __shfl_xor(lrow, 32, 64);

    if (PARTIAL) {
#pragma unroll
        for (int nt = 0; nt < 4; ++nt)
#pragma unroll
            for (int r = 0; r < 4; ++r) {
                int row = g * 4 + r;
                Opart[((size_t)sg * LSEQ + q0 + w * 16 + row) * DMODEL + h * DHEAD + nt * 16 + l16] =
                    O[nt][r];
            }
        if (lane < 16) {
            Lpart[((size_t)sg * NHEAD + h) * LSEQ + q0 + w * 16 + l16] = lrow;
        }
    } else {
        float lsr[4];
#pragma unroll
        for (int r = 0; r < 4; ++r) lsr[r] = __shfl(lrow, g * 4 + r, 64);
#pragma unroll
        for (int nt = 0; nt < 4; ++nt)
#pragma unroll
            for (int r = 0; r < 4; ++r) {
                int row = g * 4 + r;
                float o = O[nt][r] / lsr[r];
                unsigned short hi = f2bf(o);
                size_t idx = (size_t)(q0 + w * 16 + row) * DMODEL + h * DHEAD + nt * 16 + l16;
                ctx_hi[idx] = hi;
                ctx_lo[idx] = f2bf(o - bf2f(hi));
            }
    }
}

// ---------------------------------------------------------------------------
// Launch
// ---------------------------------------------------------------------------
extern "C" void kernel_launch(void* const* d_in, const int* in_sizes, int n_in,
                              void* d_out, int out_size, void* d_ws, size_t ws_size,
                              hipStream_t stream) {
    const float* x      = (const float*)d_in[0];
    const int*   seq    = (const int*)d_in[2];
    const float* ln_w   = (const float*)d_in[3];
    const float* ln_b   = (const float*)d_in[4];
    const float* w_qkv  = (const float*)d_in[5];
    const float* q_ln_w = (const float*)d_in[6];
    const float* k_ln_w = (const float*)d_in[7];
    const float* w_out  = (const float*)d_in[8];
    float* out = (float*)d_out;

    // Workspace layout (bytes). Base block = 44,040,192.
    char* ws = (char*)d_ws;
    float* qkv            = (float*)ws;                             // 18,874,368
    unsigned short* wqT_h = (unsigned short*)(ws + 18874368);       //  3,538,944
    unsigned short* wqT_l = (unsigned short*)(ws + 22413312);       //  3,538,944
    unsigned short* woT_h = (unsigned short*)(ws + 25952256);       //  1,179,648
    unsigned short* woT_l = (unsigned short*)(ws + 27131904);       //  1,179,648
    __hip_bfloat16* qh    = (__hip_bfloat16*)(ws + 28311552);       //  3,145,728
    __hip_bfloat16* kh    = (__hip_bfloat16*)(ws + 31457280);       //  3,145,728
    __hip_bfloat16* vt    = (__hip_bfloat16*)(ws + 34603008);       //  3,145,728
    unsigned short* h_hi  = (unsigned short*)(ws + 37748736);       //  3,145,728
    unsigned short* h_lo  = (unsigned short*)(ws + 40894464);       //  3,145,728 (fallback ctx_lo)
    unsigned short* ctx_hi = h_hi;
    unsigned short* ctx_lo = h_lo;

    // KV-split partials (only if workspace allows); NSEG=2
    const size_t BASE = 44040192;
    float* Opart = (float*)(ws + BASE);                             // 12,582,912
    float* Lpart = (float*)(ws + BASE + 12582912);                  //    196,608
    const size_t NEED = BASE + 12779520;
    const bool use_split = (ws_size >= NEED);

    hipLaunchKernelGGL(prep1_kernel,
                       dim3(LSEQ + (D3 / 64 + DMODEL / 64) * (DMODEL / 64)), dim3(256), 0, stream,
                       x, ln_w, ln_b, h_hi, w_qkv, wqT_h, wqT_l, w_out, woT_h, woT_l);
    hipLaunchKernelGGL(gemm_bA, dim3(D3 / 64, LSEQ / 64), dim3(256), 0, stream,
                       h_hi, wqT_h, wqT_l, qkv, LSEQ, D3, DMODEL);
    hipLaunchKernelGGL(prep2_kernel, dim3(LSEQ + 32 * NHEAD), dim3(256), 0, stream,
                       qkv, q_ln_w, k_ln_w, qh, kh, vt);
    if (use_split) {
        hipLaunchKernelGGL((attn_mfma<true>), dim3(LSEQ / 64, NHEAD, NSEG), dim3(256), 0, stream,
                           qh, kh, vt, seq, ctx_hi, ctx_lo, Opart, Lpart);
        hipLaunchKernelGGL(gemm_out_fused, dim3(DMODEL / 64, LSEQ / 64), dim3(256), 0, stream,
                           Opart, Lpart, woT_h, woT_l, out);
    } else {
        hipLaunchKernelGGL((attn_mfma<false>), dim3(LSEQ / 64, NHEAD), dim3(256), 0, stream,
                           qh, kh, vt, seq, ctx_hi, ctx_lo, Opart, Lpart);
        hipLaunchKernelGGL(gemm_split, dim3(DMODEL / 64, LSEQ / 64), dim3(256), 0, stream,
                           ctx_hi, ctx_lo, woT_h, woT_l, out, LSEQ, DMODEL, DMODEL);
    }
}

// Round 21
// 99.672 us; speedup vs baseline: 1.0493x; 1.0493x over previous
//
#include <hip/hip_runtime.h>
#include <hip/hip_bf16.h>
#include <math.h>

// Problem constants
#define LSEQ 2048
#define DMODEL 768
#define NHEAD 12
#define DHEAD 64
#define D3 2304
#define EPSLN 1e-5f
#define NSEG 2
#define SEGTILES 16      // 32 KV tiles / NSEG
#define LOG2E 1.44269504088896f

typedef __attribute__((ext_vector_type(8))) short short8;
typedef __attribute__((ext_vector_type(4))) short s16x4;
typedef __attribute__((ext_vector_type(4))) float f32x4;
typedef __attribute__((ext_vector_type(4))) unsigned short u16x4;

static __device__ __forceinline__ unsigned short f2bf(float x) {
    __hip_bfloat16 b = __float2bfloat16(x);
    return *reinterpret_cast<unsigned short*>(&b);
}
static __device__ __forceinline__ float bf2f(unsigned short u) {
    __hip_bfloat16 b = *reinterpret_cast<__hip_bfloat16*>(&u);
    return __bfloat162float(b);
}

// ---------------------------------------------------------------------------
// Kernel 1 (merged): bx < LSEQ -> LayerNorm row (bf16 hi only; lo-term dropped
// for the qkv GEMM — error is laundered through qk-LN / v-bf16-cast);
// else weight transpose + Dekker split tile (w_qkv then w_out).
// ---------------------------------------------------------------------------
__global__ __launch_bounds__(256) void prep1_kernel(const float* __restrict__ x,
                                                    const float* __restrict__ lw,
                                                    const float* __restrict__ lb,
                                                    unsigned short* __restrict__ hhi,
                                                    const float* __restrict__ Wq,
                                                    unsigned short* __restrict__ Tqh,
                                                    unsigned short* __restrict__ Tql,
                                                    const float* __restrict__ Wo,
                                                    unsigned short* __restrict__ Toh,
                                                    unsigned short* __restrict__ Tol) {
    __shared__ float smem[64 * 65];
    int bx = blockIdx.x;
    int tid = threadIdx.x;

    if (bx < LSEQ) {
        // ---- LayerNorm -> bf16 (hi only) ----
        int row = bx;
        const float* xr = x + (size_t)row * DMODEL;
        float s = 0.f, s2 = 0.f;
        for (int i = tid; i < DMODEL; i += 256) {
            float v = xr[i];
            s += v; s2 += v * v;
        }
        for (int o = 32; o > 0; o >>= 1) { s += __shfl_down(s, o); s2 += __shfl_down(s2, o); }
        int wid = tid >> 6, lane = tid & 63;
        if (lane == 0) { smem[wid] = s; smem[4 + wid] = s2; }
        __syncthreads();
        s = smem[0] + smem[1] + smem[2] + smem[3];
        s2 = smem[4] + smem[5] + smem[6] + smem[7];
        float mean = s * (1.0f / DMODEL);
        float var = s2 * (1.0f / DMODEL) - mean * mean;
        float r = rsqrtf(var + EPSLN);
        for (int i = tid; i < DMODEL; i += 256) {
            float y = (xr[i] - mean) * r * lw[i] + lb[i];
            hhi[(size_t)row * DMODEL + i] = f2bf(y);
        }
    } else {
        // ---- weight transpose + Dekker split ----
        int tb = bx - LSEQ;                 // 0 .. (36+12)*12-1
        int nt = tb % (D3 / 64 + DMODEL / 64);
        int kt = tb / (D3 / 64 + DMODEL / 64);
        const float* W;
        unsigned short *Thi, *Tlo;
        int N, n0;
        if (nt < D3 / 64) { W = Wq; Thi = Tqh; Tlo = Tql; N = D3; n0 = nt * 64; }
        else              { W = Wo; Thi = Toh; Tlo = Tol; N = DMODEL; n0 = (nt - D3 / 64) * 64; }
        const int K = DMODEL;
        int k0 = kt * 64;
        float (*tile)[65] = (float(*)[65])smem;
        for (int e = tid; e < 4096; e += 256) {
            int r = e >> 6, c = e & 63;   // r: k, c: n
            tile[r][c] = W[(size_t)(k0 + r) * N + n0 + c];
        }
        __syncthreads();
        for (int e = tid; e < 4096; e += 256) {
            int r = e >> 6, c = e & 63;   // r: n, c: k
            float v = tile[c][r];
            unsigned short hi = f2bf(v);
            size_t idx = (size_t)(n0 + r) * K + k0 + c;
            Thi[idx] = hi;
            Tlo[idx] = f2bf(v - bf2f(hi));
        }
    }
}

// ---------------------------------------------------------------------------
// Kernel 2a: GEMM with A bf16-only, B split (hi/lo): C = A @ (Bh+Bl)^T.
// 2 MFMAs per fragment pair; 24 KB LDS -> 6 blocks/CU (qkv projection).
// ---------------------------------------------------------------------------
__global__ __launch_bounds__(256) void gemm_bA(const unsigned short* __restrict__ Ahi,
                                               const unsigned short* __restrict__ Bhi,
                                               const unsigned short* __restrict__ Blo,
                                               float* __restrict__ C,
                                               int M, int N, int K) {
    __shared__ __align__(16) unsigned short Ah[64 * 64];
    __shared__ __align__(16) unsigned short Bh[64 * 64];
    __shared__ __align__(16) unsigned short Bl[64 * 64];

    int bx = blockIdx.x, by = blockIdx.y;
    int tid = threadIdx.x;
    int w = tid >> 6, lane = tid & 63;
    int g = lane >> 4, l16 = lane & 15;
    int wm = w >> 1, wn = w & 1;      // 2x2 wave grid; wave owns 32x32

    f32x4 acc[2][2] = {};

    for (int k0 = 0; k0 < K; k0 += 64) {
        __syncthreads();
#pragma unroll
        for (int c = 0; c < 2; ++c) {
            int slotb = c * 256 + w * 64;
            int slot = slotb + lane;
            int row = slot >> 3;
            int ss = (slot & 7) ^ (row & 7);     // inverse swizzle on source
            size_t offA = (size_t)(by * 64 + row) * K + k0 + ss * 8;
            size_t offB = (size_t)(bx * 64 + row) * K + k0 + ss * 8;
            __builtin_amdgcn_global_load_lds(
                (const __attribute__((address_space(1))) unsigned int*)(Ahi + offA),
                (__attribute__((address_space(3))) unsigned int*)&Ah[(size_t)slotb * 8], 16, 0, 0);
            __builtin_amdgcn_global_load_lds(
                (const __attribute__((address_space(1))) unsigned int*)(Bhi + offB),
                (__attribute__((address_space(3))) unsigned int*)&Bh[(size_t)slotb * 8], 16, 0, 0);
            __builtin_amdgcn_global_load_lds(
                (const __attribute__((address_space(1))) unsigned int*)(Blo + offB),
                (__attribute__((address_space(3))) unsigned int*)&Bl[(size_t)slotb * 8], 16, 0, 0);
        }
        __syncthreads();

#pragma unroll
        for (int kk = 0; kk < 2; ++kk) {
            short8 a_h[2], b_h[2], b_l[2];
#pragma unroll
            for (int i = 0; i < 2; ++i) {
                int row = wm * 32 + i * 16 + l16;
                int s = (kk * 4 + g) ^ (row & 7);
                a_h[i] = *(const short8*)&Ah[row * 64 + s * 8];
            }
#pragma unroll
            for (int j = 0; j < 2; ++j) {
                int row = wn * 32 + j * 16 + l16;
                int s = (kk * 4 + g) ^ (row & 7);
                b_h[j] = *(const short8*)&Bh[row * 64 + s * 8];
                b_l[j] = *(const short8*)&Bl[row * 64 + s * 8];
            }
#pragma unroll
            for (int i = 0; i < 2; ++i)
#pragma unroll
                for (int j = 0; j < 2; ++j) {
                    acc[i][j] = __builtin_amdgcn_mfma_f32_16x16x32_bf16(a_h[i], b_h[j], acc[i][j], 0, 0, 0);
                    acc[i][j] = __builtin_amdgcn_mfma_f32_16x16x32_bf16(a_h[i], b_l[j], acc[i][j], 0, 0, 0);
                }
        }
    }

#pragma unroll
    for (int i = 0; i < 2; ++i)
#pragma unroll
        for (int j = 0; j < 2; ++j)
#pragma unroll
            for (int r = 0; r < 4; ++r) {
                int m = by * 64 + wm * 32 + i * 16 + g * 4 + r;
                int n = bx * 64 + wn * 32 + j * 16 + l16;
                C[(size_t)m * N + n] = acc[i][j][r];
            }
}

// ---------------------------------------------------------------------------
// Kernel 2b: full split-bf16 GEMM (A and B hi/lo), 3 MFMAs/pair (out-proj).
// ---------------------------------------------------------------------------
__global__ __launch_bounds__(256) void gemm_split(const unsigned short* __restrict__ Ahi,
                                                  const unsigned short* __restrict__ Alo,
                                                  const unsigned short* __restrict__ Bhi,
                                                  const unsigned short* __restrict__ Blo,
                                                  float* __restrict__ C,
                                                  int M, int N, int K) {
    __shared__ __align__(16) unsigned short Ah[64 * 64];
    __shared__ __align__(16) unsigned short Al[64 * 64];
    __shared__ __align__(16) unsigned short Bh[64 * 64];
    __shared__ __align__(16) unsigned short Bl[64 * 64];

    int bx = blockIdx.x, by = blockIdx.y;
    int tid = threadIdx.x;
    int w = tid >> 6, lane = tid & 63;
    int g = lane >> 4, l16 = lane & 15;
    int wm = w >> 1, wn = w & 1;

    f32x4 acc[2][2] = {};

    for (int k0 = 0; k0 < K; k0 += 64) {
        __syncthreads();
#pragma unroll
        for (int c = 0; c < 2; ++c) {
            int slotb = c * 256 + w * 64;
            int slot = slotb + lane;
            int row = slot >> 3;
            int ss = (slot & 7) ^ (row & 7);
            size_t offA = (size_t)(by * 64 + row) * K + k0 + ss * 8;
            size_t offB = (size_t)(bx * 64 + row) * K + k0 + ss * 8;
            __builtin_amdgcn_global_load_lds(
                (const __attribute__((address_space(1))) unsigned int*)(Ahi + offA),
                (__attribute__((address_space(3))) unsigned int*)&Ah[(size_t)slotb * 8], 16, 0, 0);
            __builtin_amdgcn_global_load_lds(
                (const __attribute__((address_space(1))) unsigned int*)(Alo + offA),
                (__attribute__((address_space(3))) unsigned int*)&Al[(size_t)slotb * 8], 16, 0, 0);
            __builtin_amdgcn_global_load_lds(
                (const __attribute__((address_space(1))) unsigned int*)(Bhi + offB),
                (__attribute__((address_space(3))) unsigned int*)&Bh[(size_t)slotb * 8], 16, 0, 0);
            __builtin_amdgcn_global_load_lds(
                (const __attribute__((address_space(1))) unsigned int*)(Blo + offB),
                (__attribute__((address_space(3))) unsigned int*)&Bl[(size_t)slotb * 8], 16, 0, 0);
        }
        __syncthreads();

#pragma unroll
        for (int kk = 0; kk < 2; ++kk) {
            short8 a_h[2], a_l[2], b_h[2], b_l[2];
#pragma unroll
            for (int i = 0; i < 2; ++i) {
                int row = wm * 32 + i * 16 + l16;
                int s = (kk * 4 + g) ^ (row & 7);
                a_h[i] = *(const short8*)&Ah[row * 64 + s * 8];
                a_l[i] = *(const short8*)&Al[row * 64 + s * 8];
            }
#pragma unroll
            for (int j = 0; j < 2; ++j) {
                int row = wn * 32 + j * 16 + l16;
                int s = (kk * 4 + g) ^ (row & 7);
                b_h[j] = *(const short8*)&Bh[row * 64 + s * 8];
                b_l[j] = *(const short8*)&Bl[row * 64 + s * 8];
            }
#pragma unroll
            for (int i = 0; i < 2; ++i)
#pragma unroll
                for (int j = 0; j < 2; ++j) {
                    acc[i][j] = __builtin_amdgcn_mfma_f32_16x16x32_bf16(a_h[i], b_h[j], acc[i][j], 0, 0, 0);
                    acc[i][j] = __builtin_amdgcn_mfma_f32_16x16x32_bf16(a_h[i], b_l[j], acc[i][j], 0, 0, 0);
                    acc[i][j] = __builtin_amdgcn_mfma_f32_16x16x32_bf16(a_l[i], b_h[j], acc[i][j], 0, 0, 0);
                }
        }
    }

#pragma unroll
    for (int i = 0; i < 2; ++i)
#pragma unroll
        for (int j = 0; j < 2; ++j)
#pragma unroll
            for (int r = 0; r < 4; ++r) {
                int m = by * 64 + wm * 32 + i * 16 + g * 4 + r;
                int n = bx * 64 + wn * 32 + j * 16 + l16;
                C[(size_t)m * N + n] = acc[i][j][r];
            }
}

// ---------------------------------------------------------------------------
// Kernel 3 (merged): bx < LSEQ -> qk-LN+RoPE token; else V-transpose tile.
// Q pre-scaled by 0.125*log2e (exp2-domain scores).
// ---------------------------------------------------------------------------
__global__ __launch_bounds__(256) void prep2_kernel(const float* __restrict__ qkv,
                                                    const float* __restrict__ qw,
                                                    const float* __restrict__ kw,
                                                    __hip_bfloat16* __restrict__ qh,
                                                    __hip_bfloat16* __restrict__ kh,
                                                    __hip_bfloat16* __restrict__ vt) {
    __shared__ float smem[64 * 65];
    int bx = blockIdx.x;
    int tid = threadIdx.x;

    if (bx < LSEQ) {
        int l = bx;
        const float* qr = qkv + (size_t)l * D3;
        const float* kr = qr + DMODEL;

        float sq = 0.f, sq2 = 0.f, sk = 0.f, sk2 = 0.f;
        for (int i = tid; i < DMODEL; i += 256) {
            float a = qr[i]; sq += a; sq2 += a * a;
            float b = kr[i]; sk += b; sk2 += b * b;
        }
        for (int o = 32; o > 0; o >>= 1) {
            sq += __shfl_down(sq, o); sq2 += __shfl_down(sq2, o);
            sk += __shfl_down(sk, o); sk2 += __shfl_down(sk2, o);
        }
        int wid = tid >> 6, lane = tid & 63;
        if (lane == 0) { smem[wid] = sq; smem[4 + wid] = sq2; smem[8 + wid] = sk; smem[12 + wid] = sk2; }
        __syncthreads();
        sq = smem[0] + smem[1] + smem[2] + smem[3];
        sq2 = smem[4] + smem[5] + smem[6] + smem[7];
        sk = smem[8] + smem[9] + smem[10] + smem[11];
        sk2 = smem[12] + smem[13] + smem[14] + smem[15];
        float mq = sq * (1.0f / DMODEL);
        float vq = sq2 * (1.0f / DMODEL) - mq * mq;
        float rq = rsqrtf(vq + EPSLN);
        float mk = sk * (1.0f / DMODEL);
        float vk = sk2 * (1.0f / DMODEL) - mk * mk;
        float rk = rsqrtf(vk + EPSLN);

        const float LN10000 = 9.210340371976184f;
        const float QSCL = 0.125f * LOG2E;
        for (int p = tid; p < NHEAD * 32; p += 256) {
            int h = p >> 5, j = p & 31;
            int i1 = h * DHEAD + j;
            int i2 = i1 + 32;
            float q1 = (qr[i1] - mq) * rq * qw[i1];
            float q2 = (qr[i2] - mq) * rq * qw[i2];
            float k1 = (kr[i1] - mk) * rk * kw[i1];
            float k2 = (kr[i2] - mk) * rk * kw[i2];
            float inv = __expf(-LN10000 * (float)(2 * j) * (1.0f / DHEAD));
            float ang = (float)l * inv;
            float c, s;
            __sincosf(ang, &s, &c);
            size_t base = ((size_t)h * LSEQ + l) * DHEAD;
            qh[base + j]      = __float2bfloat16((q1 * c - q2 * s) * QSCL);
            qh[base + 32 + j] = __float2bfloat16((q2 * c + q1 * s) * QSCL);
            kh[base + j]      = __float2bfloat16(k1 * c - k2 * s);
            kh[base + 32 + j] = __float2bfloat16(k2 * c + k1 * s);
        }
    } else {
        int tb = bx - LSEQ;        // 0 .. 32*12-1
        int t = tb & 31, h = tb >> 5;
        float (*tile)[65] = (float(*)[65])smem;
        for (int e = tid; e < 4096; e += 256) {
            int tok = e >> 6, d = e & 63;
            tile[tok][d] = qkv[(size_t)(t * 64 + tok) * D3 + 2 * DMODEL + h * DHEAD + d];
        }
        __syncthreads();
        for (int e = tid; e < 4096; e += 256) {
            int d = e >> 6, tok = e & 63;
            vt[((size_t)h * DHEAD + d) * LSEQ + t * 64 + tok] = __float2bfloat16(tile[tok][d]);
        }
    }
}

// ---------------------------------------------------------------------------
// Kernel 4: MFMA flash attention, swapped QK^T, fixed-max exp2 softmax,
// in-register P, 2-phase pipelined staging, fused QK->exp2->pack.
// NSEG=2: grid 32x12x2 = 768 blocks = exactly 3/CU (no dispatch tail).
// ---------------------------------------------------------------------------
template <bool PARTIAL>
__global__ __launch_bounds__(256, 4) void attn_mfma(const __hip_bfloat16* __restrict__ qh,
                                                    const __hip_bfloat16* __restrict__ kh,
                                                    const __hip_bfloat16* __restrict__ vt,
                                                    const int* __restrict__ seq,
                                                    unsigned short* __restrict__ ctx_hi,
                                                    unsigned short* __restrict__ ctx_lo,
                                                    float* __restrict__ Opart,
                                                    float* __restrict__ Lpart) {
    int h = blockIdx.y;
    int q0 = blockIdx.x * 64;
    int sg = PARTIAL ? blockIdx.z : 0;
    int tid = threadIdx.x;
    int w = tid >> 6, lane = tid & 63;
    int g = lane >> 4, l16 = lane & 15;

    __shared__ __align__(16) unsigned short Klds[2][64 * 64];   // [tok][d] swizzled
    __shared__ __align__(16) unsigned short Vlds[2][64 * 64];   // [d][tok] swizzled
    __shared__ __align__(16) int seq_lds[2][64];

    int qrow = q0 + w * 16 + l16;
    short8 qfrag[2];
    {
        const short8* qp = (const short8*)(qh + ((size_t)h * LSEQ + qrow) * DHEAD);
        qfrag[0] = qp[g];
        qfrag[1] = qp[4 + g];
    }
    int seq_q = seq[qrow];

    f32x4 O[4] = {};
    float lrow = 0.f;

    int t0 = PARTIAL ? sg * SEGTILES : 0;
    int t1 = PARTIAL ? t0 + SEGTILES : LSEQ / 64;

    auto STAGE = [&](int buf, int t) {
#pragma unroll
        for (int i = 0; i < 2; ++i) {
            int c = 2 * w + i;
            int s = c * 64 + lane;
            int tok = s >> 3, d0 = (s & 7) * 8;
            const __hip_bfloat16* ksrc =
                kh + ((size_t)h * LSEQ + t * 64 + tok) * DHEAD + (d0 ^ ((tok & 7) << 3));
            __builtin_amdgcn_global_load_lds(
                (const __attribute__((address_space(1))) unsigned int*)ksrc,
                (__attribute__((address_space(3))) unsigned int*)&Klds[buf][c * 512],
                16, 0, 0);
            int d = s >> 3, u0 = (s & 7) * 8;
            const __hip_bfloat16* vsrc =
                vt + ((size_t)h * DHEAD + d) * LSEQ + t * 64 + (u0 ^ ((d & 7) << 3));
            __builtin_amdgcn_global_load_lds(
                (const __attribute__((address_space(1))) unsigned int*)vsrc,
                (__attribute__((address_space(3))) unsigned int*)&Vlds[buf][c * 512],
                16, 0, 0);
        }
        if (tid < 64) seq_lds[buf][tid] = seq[t * 64 + tid];
    };

    STAGE(0, t0);
    __syncthreads();   // drains vmcnt; buf0 ready for all waves

    for (int t = t0; t < t1; ++t) {
        int cur = (t - t0) & 1;
        if (t + 1 < t1) STAGE(cur ^ 1, t + 1);   // overlap with compute below

        const unsigned short* Kb = Klds[cur];
        const unsigned short* Vb = Vlds[cur];

        // ---- fused per-nt: swapped QK^T (2 MFMA) -> bias+exp2 -> pack ----
        short8 pa0, pa1;
#pragma unroll
        for (int nt = 0; nt < 4; ++nt) {
            int tok = nt * 16 + l16;
            short8 a0 = *(const short8*)&Kb[tok * 64 + ((g * 8) ^ ((tok & 7) << 3))];
            short8 a1 = *(const short8*)&Kb[tok * 64 + ((32 + g * 8) ^ ((tok & 7) << 3))];
            f32x4 acc = {0.f, 0.f, 0.f, 0.f};
            acc = __builtin_amdgcn_mfma_f32_16x16x32_bf16(a0, qfrag[0], acc, 0, 0, 0);
            acc = __builtin_amdgcn_mfma_f32_16x16x32_bf16(a1, qfrag[1], acc, 0, 0, 0);
            int4 sk4 = *(const int4*)&seq_lds[cur][nt * 16 + g * 4];
            float pv0 = exp2f(acc[0] + ((sk4.x == seq_q) ? LOG2E : 0.0f));
            float pv1 = exp2f(acc[1] + ((sk4.y == seq_q) ? LOG2E : 0.0f));
            float pv2 = exp2f(acc[2] + ((sk4.z == seq_q) ? LOG2E : 0.0f));
            float pv3 = exp2f(acc[3] + ((sk4.w == seq_q) ? LOG2E : 0.0f));
            lrow += pv0 + pv1 + pv2 + pv3;
            int hh = (nt & 1) * 4;
            if (nt < 2) {
                pa0[hh + 0] = (short)f2bf(pv0); pa0[hh + 1] = (short)f2bf(pv1);
                pa0[hh + 2] = (short)f2bf(pv2); pa0[hh + 3] = (short)f2bf(pv3);
            } else {
                pa1[hh + 0] = (short)f2bf(pv0); pa1[hh + 1] = (short)f2bf(pv1);
                pa1[hh + 2] = (short)f2bf(pv2); pa1[hh + 3] = (short)f2bf(pv3);
            }
        }

        // ---- PV: O[q][d] += P·V with the same tau permutation on V reads ----
#pragma unroll
        for (int ntd = 0; ntd < 4; ++ntd) {
            int d = ntd * 16 + l16;
            int e = (d & 7) << 1;    // granule swizzle (== staging block-XOR)
            const unsigned short* Vr = &Vb[d * 64];
            s16x4 x0 = *(const s16x4*)&Vr[((g ^ e)) << 2];
            s16x4 x1 = *(const s16x4*)&Vr[(((4 + g) ^ e)) << 2];
            s16x4 x2 = *(const s16x4*)&Vr[(((8 + g) ^ e)) << 2];
            s16x4 x3 = *(const s16x4*)&Vr[(((12 + g) ^ e)) << 2];
            short8 vb0 = __builtin_shufflevector(x0, x1, 0, 1, 2, 3, 4, 5, 6, 7);
            short8 vb1 = __builtin_shufflevector(x2, x3, 0, 1, 2, 3, 4, 5, 6, 7);
            O[ntd] = __builtin_amdgcn_mfma_f32_16x16x32_bf16(pa0, vb0, O[ntd], 0, 0, 0);
            O[ntd] = __builtin_amdgcn_mfma_f32_16x16x32_bf16(pa1, vb1, O[ntd], 0, 0, 0);
        }

        __syncthreads();   // compute(cur) done everywhere; stage(t+1) drained
    }

    // full row sum for q=l16: reduce the 4 g-copies
    lrow += __shfl_xor(lrow, 16, 64);
    lrow += __shfl_xor(lrow, 32, 64);

    if (PARTIAL) {
#pragma unroll
        for (int nt = 0; nt < 4; ++nt)
#pragma unroll
            for (int r = 0; r < 4; ++r) {
                int row = g * 4 + r;
                Opart[((size_t)sg * LSEQ + q0 + w * 16 + row) * DMODEL + h * DHEAD + nt * 16 + l16] =
                    O[nt][r];
            }
        if (lane < 16) {
            Lpart[((size_t)sg * NHEAD + h) * LSEQ + q0 + w * 16 + l16] = lrow;
        }
    } else {
        float lsr[4];
#pragma unroll
        for (int r = 0; r < 4; ++r) lsr[r] = __shfl(lrow, g * 4 + r, 64);
#pragma unroll
        for (int nt = 0; nt < 4; ++nt)
#pragma unroll
            for (int r = 0; r < 4; ++r) {
                int row = g * 4 + r;
                float o = O[nt][r] / lsr[r];
                unsigned short hi = f2bf(o);
                size_t idx = (size_t)(q0 + w * 16 + row) * DMODEL + h * DHEAD + nt * 16 + l16;
                ctx_hi[idx] = hi;
                ctx_lo[idx] = f2bf(o - bf2f(hi));
            }
    }
}

// ---------------------------------------------------------------------------
// Kernel 4b: combine NSEG partials (fixed m=0 -> plain sums) -> split ctx.
// Vectorized: one float4 of O per thread (4 elems share q and head).
// ---------------------------------------------------------------------------
__global__ __launch_bounds__(256) void attn_combine(const float* __restrict__ Opart,
                                                    const float* __restrict__ Lpart,
                                                    unsigned short* __restrict__ ctx_hi,
                                                    unsigned short* __restrict__ ctx_lo) {
    int idx4 = blockIdx.x * 256 + threadIdx.x;   // < LSEQ*DMODEL/4
    int base = idx4 * 4;
    int q = base / DMODEL;
    int c = base - q * DMODEL;
    int h = c >> 6;

    float denom = 0.f;
    float4 o = {0.f, 0.f, 0.f, 0.f};
#pragma unroll
    for (int s = 0; s < NSEG; ++s) {
        denom += Lpart[((size_t)s * NHEAD + h) * LSEQ + q];
        float4 op = *(const float4*)&Opart[((size_t)s * LSEQ + q) * DMODEL + c];
        o.x += op.x; o.y += op.y; o.z += op.z; o.w += op.w;
    }
    float rinv = 1.0f / denom;
    float r0 = o.x * rinv, r1 = o.y * rinv, r2 = o.z * rinv, r3 = o.w * rinv;
    u16x4 hi4, lo4;
    hi4[0] = f2bf(r0); lo4[0] = f2bf(r0 - bf2f(hi4[0]));
    hi4[1] = f2bf(r1); lo4[1] = f2bf(r1 - bf2f(hi4[1]));
    hi4[2] = f2bf(r2); lo4[2] = f2bf(r2 - bf2f(hi4[2]));
    hi4[3] = f2bf(r3); lo4[3] = f2bf(r3 - bf2f(hi4[3]));
    *(u16x4*)&ctx_hi[base] = hi4;
    *(u16x4*)&ctx_lo[base] = lo4;
}

// ---------------------------------------------------------------------------
// Launch
// ---------------------------------------------------------------------------
extern "C" void kernel_launch(void* const* d_in, const int* in_sizes, int n_in,
                              void* d_out, int out_size, void* d_ws, size_t ws_size,
                              hipStream_t stream) {
    const float* x      = (const float*)d_in[0];
    const int*   seq    = (const int*)d_in[2];
    const float* ln_w   = (const float*)d_in[3];
    const float* ln_b   = (const float*)d_in[4];
    const float* w_qkv  = (const float*)d_in[5];
    const float* q_ln_w = (const float*)d_in[6];
    const float* k_ln_w = (const float*)d_in[7];
    const float* w_out  = (const float*)d_in[8];
    float* out = (float*)d_out;

    // Workspace layout (bytes). Base block = 44,040,192.
    char* ws = (char*)d_ws;
    float* qkv            = (float*)ws;                             // 18,874,368
    unsigned short* wqT_h = (unsigned short*)(ws + 18874368);       //  3,538,944
    unsigned short* wqT_l = (unsigned short*)(ws + 22413312);       //  3,538,944
    unsigned short* woT_h = (unsigned short*)(ws + 25952256);       //  1,179,648
    unsigned short* woT_l = (unsigned short*)(ws + 27131904);       //  1,179,648
    __hip_bfloat16* qh    = (__hip_bfloat16*)(ws + 28311552);       //  3,145,728
    __hip_bfloat16* kh    = (__hip_bfloat16*)(ws + 31457280);       //  3,145,728
    __hip_bfloat16* vt    = (__hip_bfloat16*)(ws + 34603008);       //  3,145,728
    unsigned short* h_hi  = (unsigned short*)(ws + 37748736);       //  3,145,728
    unsigned short* h_lo  = (unsigned short*)(ws + 40894464);       //  3,145,728 (ctx_lo only)
    unsigned short* ctx_hi = h_hi;   // reuse after qkv GEMM
    unsigned short* ctx_lo = h_lo;

    // KV-split partials (only if workspace allows); NSEG=2
    const size_t BASE = 44040192;
    float* Opart = (float*)(ws + BASE);                             // 12,582,912
    float* Lpart = (float*)(ws + BASE + 12582912);                  //    196,608
    const size_t NEED = BASE + 12779520;
    const bool use_split = (ws_size >= NEED);

    hipLaunchKernelGGL(prep1_kernel,
                       dim3(LSEQ + (D3 / 64 + DMODEL / 64) * (DMODEL / 64)), dim3(256), 0, stream,
                       x, ln_w, ln_b, h_hi, w_qkv, wqT_h, wqT_l, w_out, woT_h, woT_l);
    hipLaunchKernelGGL(gemm_bA, dim3(D3 / 64, LSEQ / 64), dim3(256), 0, stream,
                       h_hi, wqT_h, wqT_l, qkv, LSEQ, D3, DMODEL);
    hipLaunchKernelGGL(prep2_kernel, dim3(LSEQ + 32 * NHEAD), dim3(256), 0, stream,
                       qkv, q_ln_w, k_ln_w, qh, kh, vt);
    if (use_split) {
        hipLaunchKernelGGL((attn_mfma<true>), dim3(LSEQ / 64, NHEAD, NSEG), dim3(256), 0, stream,
                           qh, kh, vt, seq, ctx_hi, ctx_lo, Opart, Lpart);
        hipLaunchKernelGGL(attn_combine, dim3(LSEQ * DMODEL / 1024), dim3(256), 0, stream,
                           Opart, Lpart, ctx_hi, ctx_lo);
    } else {
        hipLaunchKernelGGL((attn_mfma<false>), dim3(LSEQ / 64, NHEAD), dim3(256), 0, stream,
                           qh, kh, vt, seq, ctx_hi, ctx_lo, Opart, Lpart);
    }
    hipLaunchKernelGGL(gemm_split, dim3(DMODEL / 64, LSEQ / 64), dim3(256), 0, stream,
                       ctx_hi, ctx_lo, woT_h, woT_l, out, LSEQ, DMODEL, DMODEL);
}

// Round 22
// 94.481 us; speedup vs baseline: 1.1069x; 1.0550x over previous
//
#include <hip/hip_runtime.h>
#include <hip/hip_bf16.h>
#include <math.h>

// Problem constants
#define LSEQ 2048
#define DMODEL 768
#define NHEAD 12
#define DHEAD 64
#define D3 2304
#define EPSLN 1e-5f
#define NSEG 2
#define SEGTILES 16      // 32 KV tiles / NSEG
#define LOG2E 1.44269504088896f

typedef __attribute__((ext_vector_type(8))) short short8;
typedef __attribute__((ext_vector_type(4))) short s16x4;
typedef __attribute__((ext_vector_type(4))) float f32x4;
typedef __attribute__((ext_vector_type(4))) unsigned short u16x4;

static __device__ __forceinline__ unsigned short f2bf(float x) {
    __hip_bfloat16 b = __float2bfloat16(x);
    return *reinterpret_cast<unsigned short*>(&b);
}
static __device__ __forceinline__ float bf2f(unsigned short u) {
    __hip_bfloat16 b = *reinterpret_cast<__hip_bfloat16*>(&u);
    return __bfloat162float(b);
}

// ---------------------------------------------------------------------------
// Kernel 1 (merged): bx < LSEQ -> LayerNorm row (bf16 hi only); else weight
// transpose + Dekker split tile. Vectorized: float4 loads, u16x4 stores.
// ---------------------------------------------------------------------------
__global__ __launch_bounds__(256) void prep1_kernel(const float* __restrict__ x,
                                                    const float* __restrict__ lw,
                                                    const float* __restrict__ lb,
                                                    unsigned short* __restrict__ hhi,
                                                    const float* __restrict__ Wq,
                                                    unsigned short* __restrict__ Tqh,
                                                    unsigned short* __restrict__ Tql,
                                                    const float* __restrict__ Wo,
                                                    unsigned short* __restrict__ Toh,
                                                    unsigned short* __restrict__ Tol) {
    __shared__ float smem[64 * 65];
    int bx = blockIdx.x;
    int tid = threadIdx.x;

    if (bx < LSEQ) {
        // ---- LayerNorm -> bf16 (hi only), float4-vectorized ----
        int row = bx;
        const float4* xr4 = (const float4*)(x + (size_t)row * DMODEL);
        float4 v = {0.f, 0.f, 0.f, 0.f};
        float s = 0.f, s2 = 0.f;
        if (tid < DMODEL / 4) {
            v = xr4[tid];
            s = v.x + v.y + v.z + v.w;
            s2 = v.x * v.x + v.y * v.y + v.z * v.z + v.w * v.w;
        }
        for (int o = 32; o > 0; o >>= 1) { s += __shfl_down(s, o); s2 += __shfl_down(s2, o); }
        int wid = tid >> 6, lane = tid & 63;
        if (lane == 0) { smem[wid] = s; smem[4 + wid] = s2; }
        __syncthreads();
        s = smem[0] + smem[1] + smem[2] + smem[3];
        s2 = smem[4] + smem[5] + smem[6] + smem[7];
        float mean = s * (1.0f / DMODEL);
        float var = s2 * (1.0f / DMODEL) - mean * mean;
        float r = rsqrtf(var + EPSLN);
        if (tid < DMODEL / 4) {
            float4 w4 = ((const float4*)lw)[tid];
            float4 b4 = ((const float4*)lb)[tid];
            float y0 = (v.x - mean) * r * w4.x + b4.x;
            float y1 = (v.y - mean) * r * w4.y + b4.y;
            float y2 = (v.z - mean) * r * w4.z + b4.z;
            float y3 = (v.w - mean) * r * w4.w + b4.w;
            u16x4 h4;
            h4[0] = f2bf(y0); h4[1] = f2bf(y1); h4[2] = f2bf(y2); h4[3] = f2bf(y3);
            *(u16x4*)&hhi[(size_t)row * DMODEL + tid * 4] = h4;
        }
    } else {
        // ---- weight transpose + Dekker split, vectorized ----
        int tb = bx - LSEQ;
        int nt = tb % (D3 / 64 + DMODEL / 64);
        int kt = tb / (D3 / 64 + DMODEL / 64);
        const float* W;
        unsigned short *Thi, *Tlo;
        int N, n0;
        if (nt < D3 / 64) { W = Wq; Thi = Tqh; Tlo = Tql; N = D3; n0 = nt * 64; }
        else              { W = Wo; Thi = Toh; Tlo = Tol; N = DMODEL; n0 = (nt - D3 / 64) * 64; }
        const int K = DMODEL;
        int k0 = kt * 64;
        float (*tile)[65] = (float(*)[65])smem;
        for (int e = tid; e < 1024; e += 256) {
            int r = e >> 4, c4 = (e & 15) << 2;   // r: k, c4: n base
            float4 v = *(const float4*)&W[(size_t)(k0 + r) * N + n0 + c4];
            tile[r][c4] = v.x; tile[r][c4 + 1] = v.y;
            tile[r][c4 + 2] = v.z; tile[r][c4 + 3] = v.w;
        }
        __syncthreads();
        for (int e = tid; e < 1024; e += 256) {
            int r = e >> 4, c4 = (e & 15) << 2;   // r: n, c4: k base
            u16x4 hi4, lo4;
#pragma unroll
            for (int j = 0; j < 4; ++j) {
                float vv = tile[c4 + j][r];
                unsigned short hb = f2bf(vv);
                hi4[j] = hb;
                lo4[j] = f2bf(vv - bf2f(hb));
            }
            size_t idx = (size_t)(n0 + r) * K + k0 + c4;
            *(u16x4*)&Thi[idx] = hi4;
            *(u16x4*)&Tlo[idx] = lo4;
        }
    }
}

// ---------------------------------------------------------------------------
// Kernel 2a: GEMM with A bf16-only, B split (hi/lo): C = A @ (Bh+Bl)^T.
// ---------------------------------------------------------------------------
__global__ __launch_bounds__(256) void gemm_bA(const unsigned short* __restrict__ Ahi,
                                               const unsigned short* __restrict__ Bhi,
                                               const unsigned short* __restrict__ Blo,
                                               float* __restrict__ C,
                                               int M, int N, int K) {
    __shared__ __align__(16) unsigned short Ah[64 * 64];
    __shared__ __align__(16) unsigned short Bh[64 * 64];
    __shared__ __align__(16) unsigned short Bl[64 * 64];

    int bx = blockIdx.x, by = blockIdx.y;
    int tid = threadIdx.x;
    int w = tid >> 6, lane = tid & 63;
    int g = lane >> 4, l16 = lane & 15;
    int wm = w >> 1, wn = w & 1;

    f32x4 acc[2][2] = {};

    for (int k0 = 0; k0 < K; k0 += 64) {
        __syncthreads();
#pragma unroll
        for (int c = 0; c < 2; ++c) {
            int slotb = c * 256 + w * 64;
            int slot = slotb + lane;
            int row = slot >> 3;
            int ss = (slot & 7) ^ (row & 7);
            size_t offA = (size_t)(by * 64 + row) * K + k0 + ss * 8;
            size_t offB = (size_t)(bx * 64 + row) * K + k0 + ss * 8;
            __builtin_amdgcn_global_load_lds(
                (const __attribute__((address_space(1))) unsigned int*)(Ahi + offA),
                (__attribute__((address_space(3))) unsigned int*)&Ah[(size_t)slotb * 8], 16, 0, 0);
            __builtin_amdgcn_global_load_lds(
                (const __attribute__((address_space(1))) unsigned int*)(Bhi + offB),
                (__attribute__((address_space(3))) unsigned int*)&Bh[(size_t)slotb * 8], 16, 0, 0);
            __builtin_amdgcn_global_load_lds(
                (const __attribute__((address_space(1))) unsigned int*)(Blo + offB),
                (__attribute__((address_space(3))) unsigned int*)&Bl[(size_t)slotb * 8], 16, 0, 0);
        }
        __syncthreads();

#pragma unroll
        for (int kk = 0; kk < 2; ++kk) {
            short8 a_h[2], b_h[2], b_l[2];
#pragma unroll
            for (int i = 0; i < 2; ++i) {
                int row = wm * 32 + i * 16 + l16;
                int s = (kk * 4 + g) ^ (row & 7);
                a_h[i] = *(const short8*)&Ah[row * 64 + s * 8];
            }
#pragma unroll
            for (int j = 0; j < 2; ++j) {
                int row = wn * 32 + j * 16 + l16;
                int s = (kk * 4 + g) ^ (row & 7);
                b_h[j] = *(const short8*)&Bh[row * 64 + s * 8];
                b_l[j] = *(const short8*)&Bl[row * 64 + s * 8];
            }
#pragma unroll
            for (int i = 0; i < 2; ++i)
#pragma unroll
                for (int j = 0; j < 2; ++j) {
                    acc[i][j] = __builtin_amdgcn_mfma_f32_16x16x32_bf16(a_h[i], b_h[j], acc[i][j], 0, 0, 0);
                    acc[i][j] = __builtin_amdgcn_mfma_f32_16x16x32_bf16(a_h[i], b_l[j], acc[i][j], 0, 0, 0);
                }
        }
    }

#pragma unroll
    for (int i = 0; i < 2; ++i)
#pragma unroll
        for (int j = 0; j < 2; ++j)
#pragma unroll
            for (int r = 0; r < 4; ++r) {
                int m = by * 64 + wm * 32 + i * 16 + g * 4 + r;
                int n = bx * 64 + wn * 32 + j * 16 + l16;
                C[(size_t)m * N + n] = acc[i][j][r];
            }
}

// ---------------------------------------------------------------------------
// Kernel 2b: full split-bf16 GEMM (A and B hi/lo), 3 MFMAs/pair (out-proj).
// ---------------------------------------------------------------------------
__global__ __launch_bounds__(256) void gemm_split(const unsigned short* __restrict__ Ahi,
                                                  const unsigned short* __restrict__ Alo,
                                                  const unsigned short* __restrict__ Bhi,
                                                  const unsigned short* __restrict__ Blo,
                                                  float* __restrict__ C,
                                                  int M, int N, int K) {
    __shared__ __align__(16) unsigned short Ah[64 * 64];
    __shared__ __align__(16) unsigned short Al[64 * 64];
    __shared__ __align__(16) unsigned short Bh[64 * 64];
    __shared__ __align__(16) unsigned short Bl[64 * 64];

    int bx = blockIdx.x, by = blockIdx.y;
    int tid = threadIdx.x;
    int w = tid >> 6, lane = tid & 63;
    int g = lane >> 4, l16 = lane & 15;
    int wm = w >> 1, wn = w & 1;

    f32x4 acc[2][2] = {};

    for (int k0 = 0; k0 < K; k0 += 64) {
        __syncthreads();
#pragma unroll
        for (int c = 0; c < 2; ++c) {
            int slotb = c * 256 + w * 64;
            int slot = slotb + lane;
            int row = slot >> 3;
            int ss = (slot & 7) ^ (row & 7);
            size_t offA = (size_t)(by * 64 + row) * K + k0 + ss * 8;
            size_t offB = (size_t)(bx * 64 + row) * K + k0 + ss * 8;
            __builtin_amdgcn_global_load_lds(
                (const __attribute__((address_space(1))) unsigned int*)(Ahi + offA),
                (__attribute__((address_space(3))) unsigned int*)&Ah[(size_t)slotb * 8], 16, 0, 0);
            __builtin_amdgcn_global_load_lds(
                (const __attribute__((address_space(1))) unsigned int*)(Alo + offA),
                (__attribute__((address_space(3))) unsigned int*)&Al[(size_t)slotb * 8], 16, 0, 0);
            __builtin_amdgcn_global_load_lds(
                (const __attribute__((address_space(1))) unsigned int*)(Bhi + offB),
                (__attribute__((address_space(3))) unsigned int*)&Bh[(size_t)slotb * 8], 16, 0, 0);
            __builtin_amdgcn_global_load_lds(
                (const __attribute__((address_space(1))) unsigned int*)(Blo + offB),
                (__attribute__((address_space(3))) unsigned int*)&Bl[(size_t)slotb * 8], 16, 0, 0);
        }
        __syncthreads();

#pragma unroll
        for (int kk = 0; kk < 2; ++kk) {
            short8 a_h[2], a_l[2], b_h[2], b_l[2];
#pragma unroll
            for (int i = 0; i < 2; ++i) {
                int row = wm * 32 + i * 16 + l16;
                int s = (kk * 4 + g) ^ (row & 7);
                a_h[i] = *(const short8*)&Ah[row * 64 + s * 8];
                a_l[i] = *(const short8*)&Al[row * 64 + s * 8];
            }
#pragma unroll
            for (int j = 0; j < 2; ++j) {
                int row = wn * 32 + j * 16 + l16;
                int s = (kk * 4 + g) ^ (row & 7);
                b_h[j] = *(const short8*)&Bh[row * 64 + s * 8];
                b_l[j] = *(const short8*)&Bl[row * 64 + s * 8];
            }
#pragma unroll
            for (int i = 0; i < 2; ++i)
#pragma unroll
                for (int j = 0; j < 2; ++j) {
                    acc[i][j] = __builtin_amdgcn_mfma_f32_16x16x32_bf16(a_h[i], b_h[j], acc[i][j], 0, 0, 0);
                    acc[i][j] = __builtin_amdgcn_mfma_f32_16x16x32_bf16(a_h[i], b_l[j], acc[i][j], 0, 0, 0);
                    acc[i][j] = __builtin_amdgcn_mfma_f32_16x16x32_bf16(a_l[i], b_h[j], acc[i][j], 0, 0, 0);
                }
        }
    }

#pragma unroll
    for (int i = 0; i < 2; ++i)
#pragma unroll
        for (int j = 0; j < 2; ++j)
#pragma unroll
            for (int r = 0; r < 4; ++r) {
                int m = by * 64 + wm * 32 + i * 16 + g * 4 + r;
                int n = bx * 64 + wn * 32 + j * 16 + l16;
                C[(size_t)m * N + n] = acc[i][j][r];
            }
}

// ---------------------------------------------------------------------------
// Kernel 3 (merged): bx < LSEQ -> qk-LN+RoPE token; else V-transpose tile.
// Q pre-scaled by 0.125*log2e. Vectorized loads (float4) in both branches.
// ---------------------------------------------------------------------------
__global__ __launch_bounds__(256) void prep2_kernel(const float* __restrict__ qkv,
                                                    const float* __restrict__ qw,
                                                    const float* __restrict__ kw,
                                                    __hip_bfloat16* __restrict__ qh,
                                                    __hip_bfloat16* __restrict__ kh,
                                                    __hip_bfloat16* __restrict__ vt) {
    __shared__ float smem[64 * 65];
    int bx = blockIdx.x;
    int tid = threadIdx.x;

    if (bx < LSEQ) {
        int l = bx;
        const float* qr = qkv + (size_t)l * D3;
        const float* kr = qr + DMODEL;

        float sq = 0.f, sq2 = 0.f, sk = 0.f, sk2 = 0.f;
        if (tid < DMODEL / 4) {
            float4 a4 = ((const float4*)qr)[tid];
            float4 b4 = ((const float4*)kr)[tid];
            sq = a4.x + a4.y + a4.z + a4.w;
            sq2 = a4.x * a4.x + a4.y * a4.y + a4.z * a4.z + a4.w * a4.w;
            sk = b4.x + b4.y + b4.z + b4.w;
            sk2 = b4.x * b4.x + b4.y * b4.y + b4.z * b4.z + b4.w * b4.w;
        }
        for (int o = 32; o > 0; o >>= 1) {
            sq += __shfl_down(sq, o); sq2 += __shfl_down(sq2, o);
            sk += __shfl_down(sk, o); sk2 += __shfl_down(sk2, o);
        }
        int wid = tid >> 6, lane = tid & 63;
        if (lane == 0) { smem[wid] = sq; smem[4 + wid] = sq2; smem[8 + wid] = sk; smem[12 + wid] = sk2; }
        __syncthreads();
        sq = smem[0] + smem[1] + smem[2] + smem[3];
        sq2 = smem[4] + smem[5] + smem[6] + smem[7];
        sk = smem[8] + smem[9] + smem[10] + smem[11];
        sk2 = smem[12] + smem[13] + smem[14] + smem[15];
        float mq = sq * (1.0f / DMODEL);
        float vq = sq2 * (1.0f / DMODEL) - mq * mq;
        float rq = rsqrtf(vq + EPSLN);
        float mk = sk * (1.0f / DMODEL);
        float vk = sk2 * (1.0f / DMODEL) - mk * mk;
        float rk = rsqrtf(vk + EPSLN);

        const float LN10000 = 9.210340371976184f;
        const float QSCL = 0.125f * LOG2E;
        for (int p = tid; p < NHEAD * 32; p += 256) {
            int h = p >> 5, j = p & 31;
            int i1 = h * DHEAD + j;
            int i2 = i1 + 32;
            float q1 = (qr[i1] - mq) * rq * qw[i1];
            float q2 = (qr[i2] - mq) * rq * qw[i2];
            float k1 = (kr[i1] - mk) * rk * kw[i1];
            float k2 = (kr[i2] - mk) * rk * kw[i2];
            float inv = __expf(-LN10000 * (float)(2 * j) * (1.0f / DHEAD));
            float ang = (float)l * inv;
            float c, s;
            __sincosf(ang, &s, &c);
            size_t base = ((size_t)h * LSEQ + l) * DHEAD;
            qh[base + j]      = __float2bfloat16((q1 * c - q2 * s) * QSCL);
            qh[base + 32 + j] = __float2bfloat16((q2 * c + q1 * s) * QSCL);
            kh[base + j]      = __float2bfloat16(k1 * c - k2 * s);
            kh[base + 32 + j] = __float2bfloat16(k2 * c + k1 * s);
        }
    } else {
        int tb = bx - LSEQ;        // 0 .. 32*12-1
        int t = tb & 31, h = tb >> 5;
        float (*tile)[65] = (float(*)[65])smem;
        for (int e = tid; e < 1024; e += 256) {
            int tok = e >> 4, d4 = (e & 15) << 2;
            float4 v = *(const float4*)&qkv[(size_t)(t * 64 + tok) * D3 + 2 * DMODEL + h * DHEAD + d4];
            tile[tok][d4] = v.x; tile[tok][d4 + 1] = v.y;
            tile[tok][d4 + 2] = v.z; tile[tok][d4 + 3] = v.w;
        }
        __syncthreads();
        unsigned short* vtu = (unsigned short*)vt;
        for (int e = tid; e < 1024; e += 256) {
            int d = e >> 4, tok4 = (e & 15) << 2;
            u16x4 o4;
#pragma unroll
            for (int j = 0; j < 4; ++j) o4[j] = f2bf(tile[tok4 + j][d]);
            *(u16x4*)&vtu[((size_t)h * DHEAD + d) * LSEQ + t * 64 + tok4] = o4;
        }
    }
}

// ---------------------------------------------------------------------------
// Kernel 4: MFMA flash attention, swapped QK^T, fixed-max exp2 softmax,
// in-register P, 2-phase pipelined staging, fused QK->exp2->pack.
// NSEG=2: grid 32x12x2 = 768 blocks = exactly 3/CU (no dispatch tail).
// ---------------------------------------------------------------------------
template <bool PARTIAL>
__global__ __launch_bounds__(256, 4) void attn_mfma(const __hip_bfloat16* __restrict__ qh,
                                                    const __hip_bfloat16* __restrict__ kh,
                                                    const __hip_bfloat16* __restrict__ vt,
                                                    const int* __restrict__ seq,
                                                    unsigned short* __restrict__ ctx_hi,
                                                    unsigned short* __restrict__ ctx_lo,
                                                    float* __restrict__ Opart,
                                                    float* __restrict__ Lpart) {
    int h = blockIdx.y;
    int q0 = blockIdx.x * 64;
    int sg = PARTIAL ? blockIdx.z : 0;
    int tid = threadIdx.x;
    int w = tid >> 6, lane = tid & 63;
    int g = lane >> 4, l16 = lane & 15;

    __shared__ __align__(16) unsigned short Klds[2][64 * 64];   // [tok][d] swizzled
    __shared__ __align__(16) unsigned short Vlds[2][64 * 64];   // [d][tok] swizzled
    __shared__ __align__(16) int seq_lds[2][64];

    int qrow = q0 + w * 16 + l16;
    short8 qfrag[2];
    {
        const short8* qp = (const short8*)(qh + ((size_t)h * LSEQ + qrow) * DHEAD);
        qfrag[0] = qp[g];
        qfrag[1] = qp[4 + g];
    }
    int seq_q = seq[qrow];

    f32x4 O[4] = {};
    float lrow = 0.f;

    int t0 = PARTIAL ? sg * SEGTILES : 0;
    int t1 = PARTIAL ? t0 + SEGTILES : LSEQ / 64;

    auto STAGE = [&](int buf, int t) {
#pragma unroll
        for (int i = 0; i < 2; ++i) {
            int c = 2 * w + i;
            int s = c * 64 + lane;
            int tok = s >> 3, d0 = (s & 7) * 8;
            const __hip_bfloat16* ksrc =
                kh + ((size_t)h * LSEQ + t * 64 + tok) * DHEAD + (d0 ^ ((tok & 7) << 3));
            __builtin_amdgcn_global_load_lds(
                (const __attribute__((address_space(1))) unsigned int*)ksrc,
                (__attribute__((address_space(3))) unsigned int*)&Klds[buf][c * 512],
                16, 0, 0);
            int d = s >> 3, u0 = (s & 7) * 8;
            const __hip_bfloat16* vsrc =
                vt + ((size_t)h * DHEAD + d) * LSEQ + t * 64 + (u0 ^ ((d & 7) << 3));
            __builtin_amdgcn_global_load_lds(
                (const __attribute__((address_space(1))) unsigned int*)vsrc,
                (__attribute__((address_space(3))) unsigned int*)&Vlds[buf][c * 512],
                16, 0, 0);
        }
        if (tid < 64) seq_lds[buf][tid] = seq[t * 64 + tid];
    };

    STAGE(0, t0);
    __syncthreads();   // drains vmcnt; buf0 ready for all waves

    for (int t = t0; t < t1; ++t) {
        int cur = (t - t0) & 1;
        if (t + 1 < t1) STAGE(cur ^ 1, t + 1);   // overlap with compute below

        const unsigned short* Kb = Klds[cur];
        const unsigned short* Vb = Vlds[cur];

        // ---- fused per-nt: swapped QK^T (2 MFMA) -> bias+exp2 -> pack ----
        short8 pa0, pa1;
#pragma unroll
        for (int nt = 0; nt < 4; ++nt) {
            int tok = nt * 16 + l16;
            short8 a0 = *(const short8*)&Kb[tok * 64 + ((g * 8) ^ ((tok & 7) << 3))];
            short8 a1 = *(const short8*)&Kb[tok * 64 + ((32 + g * 8) ^ ((tok & 7) << 3))];
            f32x4 acc = {0.f, 0.f, 0.f, 0.f};
            acc = __builtin_amdgcn_mfma_f32_16x16x32_bf16(a0, qfrag[0], acc, 0, 0, 0);
            acc = __builtin_amdgcn_mfma_f32_16x16x32_bf16(a1, qfrag[1], acc, 0, 0, 0);
            int4 sk4 = *(const int4*)&seq_lds[cur][nt * 16 + g * 4];
            float pv0 = exp2f(acc[0] + ((sk4.x == seq_q) ? LOG2E : 0.0f));
            float pv1 = exp2f(acc[1] + ((sk4.y == seq_q) ? LOG2E : 0.0f));
            float pv2 = exp2f(acc[2] + ((sk4.z == seq_q) ? LOG2E : 0.0f));
            float pv3 = exp2f(acc[3] + ((sk4.w == seq_q) ? LOG2E : 0.0f));
            lrow += pv0 + pv1 + pv2 + pv3;
            int hh = (nt & 1) * 4;
            if (nt < 2) {
                pa0[hh + 0] = (short)f2bf(pv0); pa0[hh + 1] = (short)f2bf(pv1);
                pa0[hh + 2] = (short)f2bf(pv2); pa0[hh + 3] = (short)f2bf(pv3);
            } else {
                pa1[hh + 0] = (short)f2bf(pv0); pa1[hh + 1] = (short)f2bf(pv1);
                pa1[hh + 2] = (short)f2bf(pv2); pa1[hh + 3] = (short)f2bf(pv3);
            }
        }

        // ---- PV: O[q][d] += P·V with the same tau permutation on V reads ----
#pragma unroll
        for (int ntd = 0; ntd < 4; ++ntd) {
            int d = ntd * 16 + l16;
            int e = (d & 7) << 1;    // granule swizzle (== staging block-XOR)
            const unsigned short* Vr = &Vb[d * 64];
            s16x4 x0 = *(const s16x4*)&Vr[((g ^ e)) << 2];
            s16x4 x1 = *(const s16x4*)&Vr[(((4 + g) ^ e)) << 2];
            s16x4 x2 = *(const s16x4*)&Vr[(((8 + g) ^ e)) << 2];
            s16x4 x3 = *(const s16x4*)&Vr[(((12 + g) ^ e)) << 2];
            short8 vb0 = __builtin_shufflevector(x0, x1, 0, 1, 2, 3, 4, 5, 6, 7);
            short8 vb1 = __builtin_shufflevector(x2, x3, 0, 1, 2, 3, 4, 5, 6, 7);
            O[ntd] = __builtin_amdgcn_mfma_f32_16x16x32_bf16(pa0, vb0, O[ntd], 0, 0, 0);
            O[ntd] = __builtin_amdgcn_mfma_f32_16x16x32_bf16(pa1, vb1, O[ntd], 0, 0, 0);
        }

        __syncthreads();   // compute(cur) done everywhere; stage(t+1) drained
    }

    // full row sum for q=l16: reduce the 4 g-copies
    lrow += __shfl_xor(lrow, 16, 64);
    lrow += __shfl_xor(lrow, 32, 64);

    if (PARTIAL) {
#pragma unroll
        for (int nt = 0; nt < 4; ++nt)
#pragma unroll
            for (int r = 0; r < 4; ++r) {
                int row = g * 4 + r;
                Opart[((size_t)sg * LSEQ + q0 + w * 16 + row) * DMODEL + h * DHEAD + nt * 16 + l16] =
                    O[nt][r];
            }
        if (lane < 16) {
            Lpart[((size_t)sg * NHEAD + h) * LSEQ + q0 + w * 16 + l16] = lrow;
        }
    } else {
        float lsr[4];
#pragma unroll
        for (int r = 0; r < 4; ++r) lsr[r] = __shfl(lrow, g * 4 + r, 64);
#pragma unroll
        for (int nt = 0; nt < 4; ++nt)
#pragma unroll
            for (int r = 0; r < 4; ++r) {
                int row = g * 4 + r;
                float o = O[nt][r] / lsr[r];
                unsigned short hi = f2bf(o);
                size_t idx = (size_t)(q0 + w * 16 + row) * DMODEL + h * DHEAD + nt * 16 + l16;
                ctx_hi[idx] = hi;
                ctx_lo[idx] = f2bf(o - bf2f(hi));
            }
    }
}

// ---------------------------------------------------------------------------
// Kernel 4b: combine NSEG partials (fixed m=0 -> plain sums) -> split ctx.
// Vectorized: one float4 of O per thread (4 elems share q and head).
// ---------------------------------------------------------------------------
__global__ __launch_bounds__(256) void attn_combine(const float* __restrict__ Opart,
                                                    const float* __restrict__ Lpart,
                                                    unsigned short* __restrict__ ctx_hi,
                                                    unsigned short* __restrict__ ctx_lo) {
    int idx4 = blockIdx.x * 256 + threadIdx.x;   // < LSEQ*DMODEL/4
    int base = idx4 * 4;
    int q = base / DMODEL;
    int c = base - q * DMODEL;
    int h = c >> 6;

    float denom = 0.f;
    float4 o = {0.f, 0.f, 0.f, 0.f};
#pragma unroll
    for (int s = 0; s < NSEG; ++s) {
        denom += Lpart[((size_t)s * NHEAD + h) * LSEQ + q];
        float4 op = *(const float4*)&Opart[((size_t)s * LSEQ + q) * DMODEL + c];
        o.x += op.x; o.y += op.y; o.z += op.z; o.w += op.w;
    }
    float rinv = 1.0f / denom;
    float r0 = o.x * rinv, r1 = o.y * rinv, r2 = o.z * rinv, r3 = o.w * rinv;
    u16x4 hi4, lo4;
    hi4[0] = f2bf(r0); lo4[0] = f2bf(r0 - bf2f(hi4[0]));
    hi4[1] = f2bf(r1); lo4[1] = f2bf(r1 - bf2f(hi4[1]));
    hi4[2] = f2bf(r2); lo4[2] = f2bf(r2 - bf2f(hi4[2]));
    hi4[3] = f2bf(r3); lo4[3] = f2bf(r3 - bf2f(hi4[3]));
    *(u16x4*)&ctx_hi[base] = hi4;
    *(u16x4*)&ctx_lo[base] = lo4;
}

// ---------------------------------------------------------------------------
// Launch
// ---------------------------------------------------------------------------
extern "C" void kernel_launch(void* const* d_in, const int* in_sizes, int n_in,
                              void* d_out, int out_size, void* d_ws, size_t ws_size,
                              hipStream_t stream) {
    const float* x      = (const float*)d_in[0];
    const int*   seq    = (const int*)d_in[2];
    const float* ln_w   = (const float*)d_in[3];
    const float* ln_b   = (const float*)d_in[4];
    const float* w_qkv  = (const float*)d_in[5];
    const float* q_ln_w = (const float*)d_in[6];
    const float* k_ln_w = (const float*)d_in[7];
    const float* w_out  = (const float*)d_in[8];
    float* out = (float*)d_out;

    // Workspace layout (bytes). Base block = 44,040,192.
    char* ws = (char*)d_ws;
    float* qkv            = (float*)ws;                             // 18,874,368
    unsigned short* wqT_h = (unsigned short*)(ws + 18874368);       //  3,538,944
    unsigned short* wqT_l = (unsigned short*)(ws + 22413312);       //  3,538,944
    unsigned short* woT_h = (unsigned short*)(ws + 25952256);       //  1,179,648
    unsigned short* woT_l = (unsigned short*)(ws + 27131904);       //  1,179,648
    __hip_bfloat16* qh    = (__hip_bfloat16*)(ws + 28311552);       //  3,145,728
    __hip_bfloat16* kh    = (__hip_bfloat16*)(ws + 31457280);       //  3,145,728
    __hip_bfloat16* vt    = (__hip_bfloat16*)(ws + 34603008);       //  3,145,728
    unsigned short* h_hi  = (unsigned short*)(ws + 37748736);       //  3,145,728
    unsigned short* h_lo  = (unsigned short*)(ws + 40894464);       //  3,145,728 (ctx_lo only)
    unsigned short* ctx_hi = h_hi;   // reuse after qkv GEMM
    unsigned short* ctx_lo = h_lo;

    // KV-split partials (only if workspace allows); NSEG=2
    const size_t BASE = 44040192;
    float* Opart = (float*)(ws + BASE);                             // 12,582,912
    float* Lpart = (float*)(ws + BASE + 12582912);                  //    196,608
    const size_t NEED = BASE + 12779520;
    const bool use_split = (ws_size >= NEED);

    hipLaunchKernelGGL(prep1_kernel,
                       dim3(LSEQ + (D3 / 64 + DMODEL / 64) * (DMODEL / 64)), dim3(256), 0, stream,
                       x, ln_w, ln_b, h_hi, w_qkv, wqT_h, wqT_l, w_out, woT_h, woT_l);
    hipLaunchKernelGGL(gemm_bA, dim3(D3 / 64, LSEQ / 64), dim3(256), 0, stream,
                       h_hi, wqT_h, wqT_l, qkv, LSEQ, D3, DMODEL);
    hipLaunchKernelGGL(prep2_kernel, dim3(LSEQ + 32 * NHEAD), dim3(256), 0, stream,
                       qkv, q_ln_w, k_ln_w, qh, kh, vt);
    if (use_split) {
        hipLaunchKernelGGL((attn_mfma<true>), dim3(LSEQ / 64, NHEAD, NSEG), dim3(256), 0, stream,
                           qh, kh, vt, seq, ctx_hi, ctx_lo, Opart, Lpart);
        hipLaunchKernelGGL(attn_combine, dim3(LSEQ * DMODEL / 1024), dim3(256), 0, stream,
                           Opart, Lpart, ctx_hi, ctx_lo);
    } else {
        hipLaunchKernelGGL((attn_mfma<false>), dim3(LSEQ / 64, NHEAD), dim3(256), 0, stream,
                           qh, kh, vt, seq, ctx_hi, ctx_lo, Opart, Lpart);
    }
    hipLaunchKernelGGL(gemm_split, dim3(DMODEL / 64, LSEQ / 64), dim3(256), 0, stream,
                       ctx_hi, ctx_lo, woT_h, woT_l, out, LSEQ, DMODEL, DMODEL);
}